// Round 2
// baseline (313.280 us; speedup 1.0000x reference)
//
#include <hip/hip_runtime.h>
#include <hip/hip_bf16.h>
#include <stdint.h>

// CRF nllh = sum_b (logZ_b - score_b).
// logZ via chunked parallel scan in probability domain:
//   alpha_t = alpha_{t-1} * Q_t,  Q_t[i][j] = exp(trans[i][j]/w_{t-1} + em_t[j])
// 32 chunks of 64 steps: chunk computes X_c = (Q_{t0}..Q_{t1-1})^T via bf16 MFMA
// (X <- Q^T X), scalar rescale every 8 steps (log2 offset tracked).
// Gold-path score terms for t in the chunk are fused into the same loop
// (emission row is already in registers; tag-gather via shfl).
// Combine kernel: alpha0 through the 32 chunk matrices per batch + t=0 score.

#define T_DIM 2048
#define B_DIM 256
#define M_DIM 32
#define CHUNKS 32
#define CLEN 64

typedef __attribute__((ext_vector_type(8))) short short8;
typedef __attribute__((ext_vector_type(4))) float f32x4;

__device__ __forceinline__ int pack_bf16(float lo, float hi) {
  union { float f; uint32_t u; } a, b;
  a.f = lo; b.f = hi;
  // low16 = bf16(lo), high16 = bf16(hi); truncation rounding
  return (int)__builtin_amdgcn_perm(b.u, a.u, 0x07060302u);
}

__global__ void zero_out(float* o) { *o = 0.f; }

// ---------------- chunk matrix products (MFMA) + fused score ----------------
// 256 threads = 4 independent waves, each handling one (chunk c, batch b) unit.
__global__ __launch_bounds__(256, 8) void chunk_kernel(
    const float* __restrict__ em, const int* __restrict__ tags,
    const float* __restrict__ wt, const int* __restrict__ mask,
    const float* __restrict__ trans, const float* __restrict__ endt,
    uint32_t* __restrict__ mats, float* __restrict__ offs,
    float* __restrict__ out)
{
  const float INV_LN2 = 1.44269504088896340736f;
  int tid = threadIdx.x;
  int lane = tid & 63;
  int q = lane >> 4, m = lane & 15;
  int unit = blockIdx.x * 4 + (tid >> 6);   // = c*B + b
  int b = unit & (B_DIM - 1);
  int c = unit >> 8;
  int t0 = 1 + c * CLEN;
  int t1 = t0 + CLEN; if (t1 > T_DIM) t1 = T_DIM;

  // constant A-side transitions: t2v[I*8+j] = trans[(q*8+j)][m+16I] * INV_LN2
  float t2v[16];
#pragma unroll
  for (int I = 0; I < 2; ++I)
#pragma unroll
    for (int j = 0; j < 8; ++j)
      t2v[I * 8 + j] = trans[(q * 8 + j) * 32 + m + 16 * I] * INV_LN2;

  // X = identity; D/C layout: tile(I,J): row=16I+4q+p, col=16J+m
  f32x4 X[2][2];
#pragma unroll
  for (int I = 0; I < 2; ++I)
#pragma unroll
    for (int J = 0; J < 2; ++J)
#pragma unroll
      for (int p = 0; p < 4; ++p)
        X[I][J][p] = (I == J && (4 * q + p) == m) ? 1.f : 0.f;

  float off2 = 0.f;   // accumulated log2 rescale offset
  float ssc = 0.f;    // gold-path score partial (natural log domain)
  const int idxA = (((2 * q) & 3) * 16 + m) * 4;      // src lane*4 for B ints 0,1
  const int idxB = (((2 * q + 1) & 3) * 16 + m) * 4;  // src lane*4 for B ints 2,3
  const bool lowhalf = (lane < 32);

  // previous-step substituted tag (t0-1) and current-step mask
  int mkp = mask[(t0 - 1) * B_DIM + b];
  int tgp = mkp ? tags[(t0 - 1) * B_DIM + b] : 1;
  int mk = mask[t0 * B_DIM + b];

  for (int t = t0; t < t1; ++t) {
    int mk_next = (t + 1 < T_DIM) ? mask[(t + 1) * B_DIM + b] : 0;
    int tgt = mk ? tags[t * B_DIM + b] : 1;
    if (mk) {
      float r = __builtin_amdgcn_rcpf(wt[(t - 1) * B_DIM + b]);
      const float* emrow = em + ((size_t)(t * B_DIM + b)) * 32;
      float ea0 = emrow[m];        // natural-domain emission, cols m / m+16
      float eb0 = emrow[m + 16];

      // ---- fused gold-path score terms ----
      float sa = __shfl(ea0, tgt & 15);
      float sb = __shfl(eb0, tgt & 15);
      float em_tg = (tgt < 16) ? sa : sb;
      ssc += em_tg + trans[tgp * 32 + tgt] * r;

      // ---- Q^T A-fragments: A_I[m][k=8q+j] = Q[k][m+16I] ----
      float eA = ea0 * INV_LN2, eB = eb0 * INV_LN2;
      float qv[16];
#pragma unroll
      for (int j = 0; j < 8; ++j) {
        qv[j]     = __builtin_amdgcn_exp2f(fmaf(t2v[j],     r, eA));
        qv[8 + j] = __builtin_amdgcn_exp2f(fmaf(t2v[8 + j], r, eB));
      }
      union { int i[4]; short8 s; } af[2];
#pragma unroll
      for (int I = 0; I < 2; ++I)
#pragma unroll
        for (int j2 = 0; j2 < 4; ++j2)
          af[I].i[j2] = pack_bf16(qv[I * 8 + 2 * j2], qv[I * 8 + 2 * j2 + 1]);

      // pack running X to bf16 pairs (rows 4q+{0,1}, 4q+{2,3})
      int xpk[2][2][2];
#pragma unroll
      for (int I = 0; I < 2; ++I)
#pragma unroll
        for (int J = 0; J < 2; ++J) {
          xpk[I][J][0] = pack_bf16(X[I][J][0], X[I][J][1]);
          xpk[I][J][1] = pack_bf16(X[I][J][2], X[I][J][3]);
        }

      // D-layout -> B-operand layout: B_J int u holds rows 8q+2u{,+1}, col 16J+m
      union { int i[4]; short8 s; } bfr[2];
#pragma unroll
      for (int J = 0; J < 2; ++J) {
        int v00 = __builtin_amdgcn_ds_bpermute(idxA, xpk[0][J][0]);
        int v01 = __builtin_amdgcn_ds_bpermute(idxA, xpk[1][J][0]);
        int v10 = __builtin_amdgcn_ds_bpermute(idxA, xpk[0][J][1]);
        int v11 = __builtin_amdgcn_ds_bpermute(idxA, xpk[1][J][1]);
        int v20 = __builtin_amdgcn_ds_bpermute(idxB, xpk[0][J][0]);
        int v21 = __builtin_amdgcn_ds_bpermute(idxB, xpk[1][J][0]);
        int v30 = __builtin_amdgcn_ds_bpermute(idxB, xpk[0][J][1]);
        int v31 = __builtin_amdgcn_ds_bpermute(idxB, xpk[1][J][1]);
        bfr[J].i[0] = lowhalf ? v00 : v01;
        bfr[J].i[1] = lowhalf ? v10 : v11;
        bfr[J].i[2] = lowhalf ? v20 : v21;
        bfr[J].i[3] = lowhalf ? v30 : v31;
      }

      f32x4 z = {0.f, 0.f, 0.f, 0.f};
#pragma unroll
      for (int I = 0; I < 2; ++I)
#pragma unroll
        for (int J = 0; J < 2; ++J)
          X[I][J] = __builtin_amdgcn_mfma_f32_16x16x32_bf16(af[I].s, bfr[J].s, z, 0, 0, 0);
    }

    if (mk && !mk_next) ssc += endt[tgt];   // sequence-end term

    if ((t & 7) == 7) {  // rescale: keep fp32/bf16 range safe
      float mx = X[0][0][0];
#pragma unroll
      for (int I = 0; I < 2; ++I)
#pragma unroll
        for (int J = 0; J < 2; ++J)
#pragma unroll
          for (int p = 0; p < 4; ++p) mx = fmaxf(mx, X[I][J][p]);
#pragma unroll
      for (int off = 1; off < 64; off <<= 1) mx = fmaxf(mx, __shfl_xor(mx, off));
      float sc = __builtin_amdgcn_rcpf(mx);
      off2 += __builtin_amdgcn_logf(mx);  // log2
#pragma unroll
      for (int I = 0; I < 2; ++I)
#pragma unroll
        for (int J = 0; J < 2; ++J)
#pragma unroll
          for (int p = 0; p < 4; ++p) X[I][J][p] *= sc;
    }

    tgp = tgt;
    mk = mk_next;
  }

  // store X as packed bf16 row-pairs: mp[pair*32 + col] = (X[2p][col], X[2p+1][col])
  uint32_t* mp = mats + (size_t)unit * 512;
#pragma unroll
  for (int I = 0; I < 2; ++I)
#pragma unroll
    for (int J = 0; J < 2; ++J) {
      mp[(8 * I + 2 * q) * 32 + 16 * J + m]     = (uint32_t)pack_bf16(X[I][J][0], X[I][J][1]);
      mp[(8 * I + 2 * q + 1) * 32 + 16 * J + m] = (uint32_t)pack_bf16(X[I][J][2], X[I][J][3]);
    }
  if (lane == 0) {
    offs[unit] = off2;
    atomicAdd(out, -ssc);
  }
}

// ---------------- combine chunks per batch + t=0 score ----------------
__global__ __launch_bounds__(64) void combine_kernel(
    const float* __restrict__ em, const int* __restrict__ tags,
    const int* __restrict__ mask, const float* __restrict__ startt,
    const float* __restrict__ endt, const uint32_t* __restrict__ mats,
    const float* __restrict__ offs, float* __restrict__ out)
{
  const float INV_LN2 = 1.44269504088896340736f;
  const float LN2 = 0.69314718055994530942f;
  int lane = threadIdx.x;
  int j = lane & 31;  // lanes 32-63 mirror
  int b = blockIdx.x;
  int jp = j >> 1, h = j & 1;

  float a0 = (startt[j] + em[(size_t)b * 32 + j]) * INV_LN2;  // log2 domain
  float c0 = a0;
#pragma unroll
  for (int off = 1; off < 32; off <<= 1) c0 = fmaxf(c0, __shfl_xor(c0, off));
  float av = __builtin_amdgcn_exp2f(a0 - c0);
  float acc = c0;  // accumulated log2 offset

  for (int c = 0; c < CHUNKS; ++c) {
    // row j of X_c = half h of packed row-pair jp
    const uint4* xr = (const uint4*)(mats + (size_t)(c * B_DIM + b) * 512 + jp * 32);
    float x[32];
#pragma unroll
    for (int k = 0; k < 8; ++k) {
      uint4 v = xr[k];
      uint32_t u[4] = {v.x, v.y, v.z, v.w};
#pragma unroll
      for (int e = 0; e < 4; ++e) {
        uint32_t bits = h ? (u[e] & 0xFFFF0000u) : (u[e] << 16);
        union { uint32_t u; float f; } cv; cv.u = bits;
        x[4 * k + e] = cv.f;
      }
    }
    float an = 0.f;
#pragma unroll
    for (int i = 0; i < 32; ++i) an = fmaf(x[i], __shfl(av, i), an);
    float mx = an;
#pragma unroll
    for (int off = 1; off < 32; off <<= 1) mx = fmaxf(mx, __shfl_xor(mx, off));
    av = an * __builtin_amdgcn_rcpf(mx);
    acc += __builtin_amdgcn_logf(mx) + offs[c * B_DIM + b];
  }

  float sv = av * __builtin_amdgcn_exp2f(endt[j] * INV_LN2);
#pragma unroll
  for (int off = 1; off < 32; off <<= 1) sv += __shfl_xor(sv, off);
  if (lane == 0) {
    float logZ = (acc + __builtin_amdgcn_logf(sv)) * LN2;
    // t=0 gold-path score terms
    int mk0 = mask[b];
    int tg0 = mk0 ? tags[b] : 1;
    float s0 = startt[tg0] + (mk0 ? em[(size_t)b * 32 + tg0] : 0.f);
    int mk1 = mask[B_DIM + b];
    if (mk0 && !mk1) s0 += endt[tg0];
    atomicAdd(out, logZ - s0);
  }
}

extern "C" void kernel_launch(void* const* d_in, const int* in_sizes, int n_in,
                              void* d_out, int out_size, void* d_ws, size_t ws_size,
                              hipStream_t stream) {
  const float* em   = (const float*)d_in[0];
  const int*   tags = (const int*)d_in[1];
  const float* wt   = (const float*)d_in[2];
  const int*   mask = (const int*)d_in[3];
  const float* tr   = (const float*)d_in[4];
  const float* stt  = (const float*)d_in[5];
  const float* ent  = (const float*)d_in[6];
  float* out = (float*)d_out;

  float* offs = (float*)d_ws;                        // CHUNKS*B floats (32 KB)
  uint32_t* mats = (uint32_t*)(offs + CHUNKS * B_DIM); // CHUNKS*B*512 u32 (~16.8 MB)

  zero_out<<<1, 1, 0, stream>>>(out);
  chunk_kernel<<<(CHUNKS * B_DIM) / 4, 256, 0, stream>>>(em, tags, wt, mask, tr, ent, mats, offs, out);
  combine_kernel<<<B_DIM, 64, 0, stream>>>(em, tags, mask, stt, ent, mats, offs, out);
}

// Round 3
// 288.933 us; speedup vs baseline: 1.0843x; 1.0843x over previous
//
#include <hip/hip_runtime.h>
#include <hip/hip_bf16.h>
#include <stdint.h>

// CRF nllh = sum_b (logZ_b - score_b).
// logZ via chunked parallel scan in probability domain:
//   alpha_t = alpha_{t-1} * Q_t,  Q_t[i][j] = exp(trans[i][j]/w_{t-1} + em_t[j])
// 32 chunks of 64 steps: chunk computes X_c = (Q_{t0}..Q_{t1-1})^T via bf16 MFMA
// (X <- Q^T X), scalar rescale every 8 steps (log2 offset tracked).
// Q entries are built as bf16 BITS directly via a Schraudolph exp2 bit-trick:
//   bf16bits(exp(x)) ~= (int)(128/ln2 * x + 16249.16)   (mean-centered, trunc-comp)
// Gold-path score runs as a lane-per-timestep epilogue in the same kernel.
// Combine kernel: alpha0 through the 32 chunk matrices per batch + t=0 score.

#define T_DIM 2048
#define B_DIM 256
#define M_DIM 32
#define CHUNKS 32
#define CLEN 64
#define KSC 184.6649652337873f   /* 128 / ln2 */
#define SBIAS 16249.16f          /* 127*128 - 7.34 (log-mean center) + 0.5 (trunc) */

typedef __attribute__((ext_vector_type(8))) short short8;
typedef __attribute__((ext_vector_type(4))) float f32x4;

__device__ __forceinline__ int pack_bf16(float lo, float hi) {
  union { float f; uint32_t u; } a, b;
  a.f = lo; b.f = hi;
  // low16 = bf16(lo), high16 = bf16(hi); truncation rounding
  return (int)__builtin_amdgcn_perm(b.u, a.u, 0x07060302u);
}

__device__ __forceinline__ int pack_lo16(int lo, int hi) {
  // (lo & 0xffff) | (hi << 16)
  return (int)__builtin_amdgcn_perm((uint32_t)hi, (uint32_t)lo, 0x05040100u);
}

// ---------------- chunk matrix products (MFMA) + score epilogue ----------------
// 256 threads = 4 independent waves, each handling one (chunk c, batch b) unit.
__global__ __launch_bounds__(256, 8) void chunk_kernel(
    const float* __restrict__ em, const int* __restrict__ tags,
    const float* __restrict__ wt, const int* __restrict__ mask,
    const float* __restrict__ trans, const float* __restrict__ endt,
    uint32_t* __restrict__ mats, float* __restrict__ offs,
    float* __restrict__ out)
{
  int tid = threadIdx.x;
  int lane = tid & 63;
  int q = lane >> 4, m = lane & 15;
  int unit = blockIdx.x * 4 + (tid >> 6);   // = c*B + b
  int b = unit & (B_DIM - 1);
  int c = unit >> 8;
  int t0 = 1 + c * CLEN;
  int t1 = t0 + CLEN; if (t1 > T_DIM) t1 = T_DIM;

  // constant A-side transitions, pre-scaled for the exp2 bit-trick:
  // tpre[I*8+j] = trans[(q*8+j)][m+16I] * (128/ln2)
  float tpre[16];
#pragma unroll
  for (int I = 0; I < 2; ++I)
#pragma unroll
    for (int j = 0; j < 8; ++j)
      tpre[I * 8 + j] = trans[(q * 8 + j) * 32 + m + 16 * I] * KSC;

  // X = identity; D/C layout: tile(I,J): row=16I+4q+p, col=16J+m
  f32x4 X[2][2];
#pragma unroll
  for (int I = 0; I < 2; ++I)
#pragma unroll
    for (int J = 0; J < 2; ++J)
#pragma unroll
      for (int p = 0; p < 4; ++p)
        X[I][J][p] = (I == J && (4 * q + p) == m) ? 1.f : 0.f;

  float off2 = 0.f;   // accumulated log2 rescale offset
  const int idxA = (((2 * q) & 3) * 16 + m) * 4;      // src lane*4 for B ints 0,1
  const int idxB = (((2 * q + 1) & 3) * 16 + m) * 4;  // src lane*4 for B ints 2,3
  const bool lowhalf = (lane < 32);

  for (int t = t0; t < t1; ++t) {
    int mk = mask[t * B_DIM + b];
    if (mk) {
      float r = __builtin_amdgcn_rcpf(wt[(t - 1) * B_DIM + b]);
      const float* emrow = em + ((size_t)(t * B_DIM + b)) * 32;
      // empre = em * (128/ln2) + SBIAS
      float eA = fmaf(emrow[m],      KSC, SBIAS);
      float eB = fmaf(emrow[m + 16], KSC, SBIAS);

      // Q^T A-fragments via exp2 bit-trick: bits = (int)(tpre*r + empre)
      int qb[16];
#pragma unroll
      for (int j = 0; j < 8; ++j) {
        qb[j]     = (int)fmaf(tpre[j],     r, eA);
        qb[8 + j] = (int)fmaf(tpre[8 + j], r, eB);
      }
      union { int i[4]; short8 s; } af[2];
#pragma unroll
      for (int I = 0; I < 2; ++I)
#pragma unroll
        for (int j2 = 0; j2 < 4; ++j2)
          af[I].i[j2] = pack_lo16(qb[I * 8 + 2 * j2], qb[I * 8 + 2 * j2 + 1]);

      // pack running X to bf16 pairs (rows 4q+{0,1}, 4q+{2,3})
      int xpk[2][2][2];
#pragma unroll
      for (int I = 0; I < 2; ++I)
#pragma unroll
        for (int J = 0; J < 2; ++J) {
          xpk[I][J][0] = pack_bf16(X[I][J][0], X[I][J][1]);
          xpk[I][J][1] = pack_bf16(X[I][J][2], X[I][J][3]);
        }

      // D-layout -> B-operand layout: B_J int u holds rows 8q+2u{,+1}, col 16J+m
      union { int i[4]; short8 s; } bfr[2];
#pragma unroll
      for (int J = 0; J < 2; ++J) {
        int v00 = __builtin_amdgcn_ds_bpermute(idxA, xpk[0][J][0]);
        int v01 = __builtin_amdgcn_ds_bpermute(idxA, xpk[1][J][0]);
        int v10 = __builtin_amdgcn_ds_bpermute(idxA, xpk[0][J][1]);
        int v11 = __builtin_amdgcn_ds_bpermute(idxA, xpk[1][J][1]);
        int v20 = __builtin_amdgcn_ds_bpermute(idxB, xpk[0][J][0]);
        int v21 = __builtin_amdgcn_ds_bpermute(idxB, xpk[1][J][0]);
        int v30 = __builtin_amdgcn_ds_bpermute(idxB, xpk[0][J][1]);
        int v31 = __builtin_amdgcn_ds_bpermute(idxB, xpk[1][J][1]);
        bfr[J].i[0] = lowhalf ? v00 : v01;
        bfr[J].i[1] = lowhalf ? v10 : v11;
        bfr[J].i[2] = lowhalf ? v20 : v21;
        bfr[J].i[3] = lowhalf ? v30 : v31;
      }

      f32x4 z = {0.f, 0.f, 0.f, 0.f};
#pragma unroll
      for (int I = 0; I < 2; ++I)
#pragma unroll
        for (int J = 0; J < 2; ++J)
          X[I][J] = __builtin_amdgcn_mfma_f32_16x16x32_bf16(af[I].s, bfr[J].s, z, 0, 0, 0);
    }

    if ((t & 7) == 7) {  // rescale: keep fp32/bf16 range safe
      float mx = X[0][0][0];
#pragma unroll
      for (int I = 0; I < 2; ++I)
#pragma unroll
        for (int J = 0; J < 2; ++J)
#pragma unroll
          for (int p = 0; p < 4; ++p) mx = fmaxf(mx, X[I][J][p]);
#pragma unroll
      for (int off = 1; off < 64; off <<= 1) mx = fmaxf(mx, __shfl_xor(mx, off));
      float sc = __builtin_amdgcn_rcpf(mx);
      off2 += __builtin_amdgcn_logf(mx);  // log2
#pragma unroll
      for (int I = 0; I < 2; ++I)
#pragma unroll
        for (int J = 0; J < 2; ++J)
#pragma unroll
          for (int p = 0; p < 4; ++p) X[I][J][p] *= sc;
    }
  }

  // store X as packed bf16 row-pairs: mp[pair*32 + col] = (X[2p][col], X[2p+1][col])
  uint32_t* mp = mats + (size_t)unit * 512;
#pragma unroll
  for (int I = 0; I < 2; ++I)
#pragma unroll
    for (int J = 0; J < 2; ++J) {
      mp[(8 * I + 2 * q) * 32 + 16 * J + m]     = (uint32_t)pack_bf16(X[I][J][0], X[I][J][1]);
      mp[(8 * I + 2 * q + 1) * 32 + 16 * J + m] = (uint32_t)pack_bf16(X[I][J][2], X[I][J][3]);
    }
  if (lane == 0) offs[unit] = off2;

  // ---- score epilogue: one lane per timestep of this wave's range ----
  int t = t0 + lane;
  float ssc = 0.f;
  if (t < T_DIM) {
    int mk  = mask[t * B_DIM + b];
    int mkn = (t + 1 < T_DIM) ? mask[(t + 1) * B_DIM + b] : 0;
    int tg  = mk ? tags[t * B_DIM + b] : 1;
    int mkp = mask[(t - 1) * B_DIM + b];
    int tgp = mkp ? tags[(t - 1) * B_DIM + b] : 1;
    float w = wt[(t - 1) * B_DIM + b];
    if (mk)
      ssc = em[(size_t)(t * B_DIM + b) * 32 + tg]
          + trans[tgp * 32 + tg] * __builtin_amdgcn_rcpf(w);
    if (mk && !mkn) ssc += endt[tg];
  }
#pragma unroll
  for (int off = 32; off; off >>= 1) ssc += __shfl_xor(ssc, off);
  if (lane == 0) atomicAdd(out, -ssc);
}

// ---------------- combine chunks per batch + t=0 score ----------------
__global__ __launch_bounds__(64) void combine_kernel(
    const float* __restrict__ em, const int* __restrict__ tags,
    const int* __restrict__ mask, const float* __restrict__ startt,
    const float* __restrict__ endt, const uint32_t* __restrict__ mats,
    const float* __restrict__ offs, float* __restrict__ out)
{
  const float INV_LN2 = 1.44269504088896340736f;
  const float LN2 = 0.69314718055994530942f;
  int lane = threadIdx.x;
  int j = lane & 31;          // row handled by this lane (both halves hold av_j)
  int h = lane >> 5;          // which 16-column half this lane accumulates
  int b = blockIdx.x;
  int jp = j >> 1, jh = j & 1;

  float a0 = (startt[j] + em[(size_t)b * 32 + j]) * INV_LN2;  // log2 domain
  float c0 = a0;
#pragma unroll
  for (int off = 1; off < 32; off <<= 1) c0 = fmaxf(c0, __shfl_xor(c0, off));
  float av = __builtin_amdgcn_exp2f(a0 - c0);
  float acc = c0;  // accumulated log2 offset

  for (int c = 0; c < CHUNKS; ++c) {
    // row j of X_c, columns [16h, 16h+16): packed row-pair jp, half jh
    const uint4* xr = (const uint4*)(mats + (size_t)(c * B_DIM + b) * 512 + jp * 32 + 16 * h);
    float x[16];
#pragma unroll
    for (int k = 0; k < 2; ++k) {
      uint4 v = xr[k];
      uint32_t u[4] = {v.x, v.y, v.z, v.w};
#pragma unroll
      for (int e = 0; e < 4; ++e) {
        uint32_t bits = jh ? (u[e] & 0xFFFF0000u) : (u[e] << 16);
        union { uint32_t uu; float f; } cv; cv.uu = bits;
        x[4 * k + e] = cv.f;
      }
    }
    float s0 = 0.f, s1 = 0.f;
#pragma unroll
    for (int i = 0; i < 8; ++i) {
      s0 = fmaf(x[2 * i],     __shfl(av, 16 * h + 2 * i),     s0);
      s1 = fmaf(x[2 * i + 1], __shfl(av, 16 * h + 2 * i + 1), s1);
    }
    float an = s0 + s1;
    an += __shfl_xor(an, 32);   // combine the two column-halves
    float mx = an;
#pragma unroll
    for (int off = 1; off < 32; off <<= 1) mx = fmaxf(mx, __shfl_xor(mx, off));
    av = an * __builtin_amdgcn_rcpf(mx);
    acc += __builtin_amdgcn_logf(mx) + offs[c * B_DIM + b];
  }

  float sv = av * __builtin_amdgcn_exp2f(endt[j] * INV_LN2);
#pragma unroll
  for (int off = 1; off < 32; off <<= 1) sv += __shfl_xor(sv, off);
  if (lane == 0) {
    float logZ = (acc + __builtin_amdgcn_logf(sv)) * LN2;
    // t=0 gold-path score terms
    int mk0 = mask[b];
    int tg0 = mk0 ? tags[b] : 1;
    float s0 = startt[tg0] + (mk0 ? em[(size_t)b * 32 + tg0] : 0.f);
    int mk1 = mask[B_DIM + b];
    if (mk0 && !mk1) s0 += endt[tg0];
    atomicAdd(out, logZ - s0);
  }
}

extern "C" void kernel_launch(void* const* d_in, const int* in_sizes, int n_in,
                              void* d_out, int out_size, void* d_ws, size_t ws_size,
                              hipStream_t stream) {
  const float* em   = (const float*)d_in[0];
  const int*   tags = (const int*)d_in[1];
  const float* wt   = (const float*)d_in[2];
  const int*   mask = (const int*)d_in[3];
  const float* tr   = (const float*)d_in[4];
  const float* stt  = (const float*)d_in[5];
  const float* ent  = (const float*)d_in[6];
  float* out = (float*)d_out;

  float* offs = (float*)d_ws;                          // CHUNKS*B floats (32 KB)
  uint32_t* mats = (uint32_t*)(offs + CHUNKS * B_DIM); // CHUNKS*B*512 u32 (~16.8 MB)

  hipMemsetAsync(out, 0, sizeof(float) * out_size, stream);
  chunk_kernel<<<(CHUNKS * B_DIM) / 4, 256, 0, stream>>>(em, tags, wt, mask, tr, ent, mats, offs, out);
  combine_kernel<<<B_DIM, 64, 0, stream>>>(em, tags, mask, stt, ent, mats, offs, out);
}

// Round 4
// 258.320 us; speedup vs baseline: 1.2128x; 1.1185x over previous
//
#include <hip/hip_runtime.h>
#include <hip/hip_bf16.h>
#include <stdint.h>

// CRF nllh = sum_b (logZ_b - score_b).
// logZ via chunked parallel scan in probability domain:
//   alpha_t = alpha_{t-1} * Q_t,  Q_t[i][j] = exp(trans[i][j]/w_{t-1} + em_t[j])
// 32 chunks of 64 steps: chunk computes X_c = (Q_{t0}..Q_{t1-1})^T with
// 32x32x16 bf16 MFMA pairs (X <- Q^T X, K=32 via C-chaining), scalar rescale
// every 8 steps (log2 offset tracked). Q entries are built as bf16 BITS via a
// Schraudolph exp2 bit-trick: bf16bits(exp(x)) ~= (int)(128/ln2*x + 16249.16).
// Depth-1 software prefetch of (em,wt,mask) hides the cold-miss latency.
// D->B-operand repack: 8 packs + half-wave swap (shfl_xor 32) + selects.
// Gold-path score runs as a lane-per-timestep epilogue in the same kernel.

#define T_DIM 2048
#define B_DIM 256
#define M_DIM 32
#define CHUNKS 32
#define CLEN 64
#define KSC 184.6649652337873f   /* 128 / ln2 */
#define SBIAS 16249.16f          /* 127*128 - 7.34 (log-mean center) + 0.5 (trunc) */

typedef __attribute__((ext_vector_type(8))) short short8;
typedef __attribute__((ext_vector_type(16))) float f32x16;

__device__ __forceinline__ int pack_bf16(float lo, float hi) {
  union { float f; uint32_t u; } a, b;
  a.f = lo; b.f = hi;
  // result = bf16(lo) | bf16(hi)<<16 (truncation rounding)
  return (int)__builtin_amdgcn_perm(b.u, a.u, 0x07060302u);
}

__device__ __forceinline__ int pack_lo16(int lo, int hi) {
  // (lo & 0xffff) | (hi << 16)
  return (int)__builtin_amdgcn_perm((uint32_t)hi, (uint32_t)lo, 0x05040100u);
}

// ---------------- chunk matrix products (MFMA) + score epilogue ----------------
// 256 threads = 4 independent waves, each handling one (chunk c, batch b) unit.
__global__ __launch_bounds__(256) void chunk_kernel(
    const float* __restrict__ em, const int* __restrict__ tags,
    const float* __restrict__ wt, const int* __restrict__ mask,
    const float* __restrict__ trans, const float* __restrict__ endt,
    uint32_t* __restrict__ mats, float* __restrict__ offs,
    float* __restrict__ out)
{
  int tid = threadIdx.x;
  int lane = tid & 63;
  int h = lane >> 5;        // wave half
  int r = lane & 31;        // A-row / B-col / D-col index
  int unit = blockIdx.x * 4 + (tid >> 6);   // = c*B + b
  int b = unit & (B_DIM - 1);
  int c = unit >> 8;
  int t0 = 1 + c * CLEN;
  int t1 = t0 + CLEN; if (t1 > T_DIM) t1 = T_DIM;

  // A-side transition constants, pre-scaled for the exp2 bit-trick:
  // A1[i=r][k=8h+j] = Q[8h+j][r]   -> tpre[j]   = trans[(8h+j)][r]*KSC
  // A2[i=r][k=8h+j] = Q[16+8h+j][r]-> tpre[8+j] = trans[(16+8h+j)][r]*KSC
  float tpre[16];
#pragma unroll
  for (int j = 0; j < 8; ++j) {
    tpre[j]     = trans[(8 * h + j) * 32 + r] * KSC;
    tpre[8 + j] = trans[(16 + 8 * h + j) * 32 + r] * KSC;
  }

  // X = identity in 32x32 D/C layout: reg p holds row (p&3)+8*(p>>2)+4h, col r
  f32x16 X;
#pragma unroll
  for (int p = 0; p < 16; ++p)
    X[p] = (((p & 3) + 8 * (p >> 2) + 4 * h) == r) ? 1.f : 0.f;

  float off2 = 0.f;   // accumulated log2 rescale offset

  // depth-1 prefetch registers
  float emv = em[((size_t)(t0 * B_DIM + b)) * 32 + r];
  float wv  = wt[(t0 - 1) * B_DIM + b];
  int   mkv = mask[t0 * B_DIM + b];

  for (int t = t0; t < t1; ++t) {
    // ---- prefetch t+1 (clamped; last prefetch is wasted but harmless) ----
    int tn = (t + 1 < T_DIM) ? (t + 1) : t;
    float emv_n = em[((size_t)(tn * B_DIM + b)) * 32 + r];
    float wv_n  = wt[(tn - 1) * B_DIM + b];
    int   mkv_n = mask[tn * B_DIM + b];

    if (mkv) {
      float rw = __builtin_amdgcn_rcpf(wv);
      float e  = fmaf(emv, KSC, SBIAS);

      // Q^T A-fragments via exp2 bit-trick
      int qb[16];
#pragma unroll
      for (int j = 0; j < 16; ++j)
        qb[j] = (int)fmaf(tpre[j], rw, e);
      union { int i[4]; short8 s; } af1, af2;
#pragma unroll
      for (int u = 0; u < 4; ++u) {
        af1.i[u] = pack_lo16(qb[2 * u], qb[2 * u + 1]);
        af2.i[u] = pack_lo16(qb[8 + 2 * u], qb[8 + 2 * u + 1]);
      }

      // pack running X rows (reg-pairs) to bf16
      int p[8];
#pragma unroll
      for (int u = 0; u < 8; ++u)
        p[u] = pack_bf16(X[2 * u], X[2 * u + 1]);

      // D-layout -> B-operand: half-wave swap of the cross rows
      int v0 = h ? p[0] : p[2];
      int v1 = h ? p[1] : p[3];
      int v2 = h ? p[4] : p[6];
      int v3 = h ? p[5] : p[7];
      int s0 = __shfl_xor(v0, 32);
      int s1 = __shfl_xor(v1, 32);
      int s2 = __shfl_xor(v2, 32);
      int s3 = __shfl_xor(v3, 32);
      union { int i[4]; short8 s; } b1, b2;
      b1.i[0] = h ? s0 : p[0];
      b1.i[1] = h ? s1 : p[1];
      b1.i[2] = h ? p[2] : s0;
      b1.i[3] = h ? p[3] : s1;
      b2.i[0] = h ? s2 : p[4];
      b2.i[1] = h ? s3 : p[5];
      b2.i[2] = h ? p[6] : s2;
      b2.i[3] = h ? p[7] : s3;

      f32x16 z;
#pragma unroll
      for (int u = 0; u < 16; ++u) z[u] = 0.f;
      f32x16 d = __builtin_amdgcn_mfma_f32_32x32x16_bf16(af1.s, b1.s, z, 0, 0, 0);
      X = __builtin_amdgcn_mfma_f32_32x32x16_bf16(af2.s, b2.s, d, 0, 0, 0);
    }

    if ((t & 7) == 7) {  // rescale: keep fp32/bf16 range safe
      float mx = X[0];
#pragma unroll
      for (int u = 1; u < 16; ++u) mx = fmaxf(mx, X[u]);
#pragma unroll
      for (int off = 1; off < 64; off <<= 1) mx = fmaxf(mx, __shfl_xor(mx, off));
      float sc = __builtin_amdgcn_rcpf(mx);
      off2 += __builtin_amdgcn_logf(mx);  // log2
#pragma unroll
      for (int u = 0; u < 16; ++u) X[u] *= sc;
    }

    emv = emv_n; wv = wv_n; mkv = mkv_n;
  }

  // store X as packed bf16 row-pairs: mp[pair*32 + col] = (X[2p][col], X[2p+1][col])
  uint32_t* mp = mats + (size_t)unit * 512;
#pragma unroll
  for (int u = 0; u < 8; ++u) {
    int pairIdx = (u & 1) + (u >> 1) * 4 + 2 * h;
    mp[pairIdx * 32 + r] = (uint32_t)pack_bf16(X[2 * u], X[2 * u + 1]);
  }
  if (lane == 0) offs[unit] = off2;

  // ---- score epilogue: one lane per timestep of this wave's range ----
  int t = t0 + lane;
  float ssc = 0.f;
  if (t < T_DIM) {
    int mk  = mask[t * B_DIM + b];
    int mkn = (t + 1 < T_DIM) ? mask[(t + 1) * B_DIM + b] : 0;
    int tg  = mk ? tags[t * B_DIM + b] : 1;
    int mkp = mask[(t - 1) * B_DIM + b];
    int tgp = mkp ? tags[(t - 1) * B_DIM + b] : 1;
    float w = wt[(t - 1) * B_DIM + b];
    if (mk)
      ssc = em[(size_t)(t * B_DIM + b) * 32 + tg]
          + trans[tgp * 32 + tg] * __builtin_amdgcn_rcpf(w);
    if (mk && !mkn) ssc += endt[tg];
  }
#pragma unroll
  for (int off = 32; off; off >>= 1) ssc += __shfl_xor(ssc, off);
  if (lane == 0) atomicAdd(out, -ssc);
}

// ---------------- combine chunks per batch + t=0 score ----------------
__global__ __launch_bounds__(64) void combine_kernel(
    const float* __restrict__ em, const int* __restrict__ tags,
    const int* __restrict__ mask, const float* __restrict__ startt,
    const float* __restrict__ endt, const uint32_t* __restrict__ mats,
    const float* __restrict__ offs, float* __restrict__ out)
{
  const float INV_LN2 = 1.44269504088896340736f;
  const float LN2 = 0.69314718055994530942f;
  int lane = threadIdx.x;
  int j = lane & 31;          // row handled by this lane (both halves hold av_j)
  int h = lane >> 5;          // which 16-column half this lane accumulates
  int b = blockIdx.x;
  int jp = j >> 1, jh = j & 1;

  float a0 = (startt[j] + em[(size_t)b * 32 + j]) * INV_LN2;  // log2 domain
  float c0 = a0;
#pragma unroll
  for (int off = 1; off < 32; off <<= 1) c0 = fmaxf(c0, __shfl_xor(c0, off));
  float av = __builtin_amdgcn_exp2f(a0 - c0);
  float acc = c0;  // accumulated log2 offset

  for (int c = 0; c < CHUNKS; ++c) {
    // row j of X_c, columns [16h, 16h+16): packed row-pair jp, half jh
    const uint4* xr = (const uint4*)(mats + (size_t)(c * B_DIM + b) * 512 + jp * 32 + 16 * h);
    float x[16];
#pragma unroll
    for (int k = 0; k < 2; ++k) {
      uint4 v = xr[k];
      uint32_t u[4] = {v.x, v.y, v.z, v.w};
#pragma unroll
      for (int e = 0; e < 4; ++e) {
        uint32_t bits = jh ? (u[e] & 0xFFFF0000u) : (u[e] << 16);
        union { uint32_t uu; float f; } cv; cv.uu = bits;
        x[4 * k + e] = cv.f;
      }
    }
    float s0 = 0.f, s1 = 0.f;
#pragma unroll
    for (int i = 0; i < 8; ++i) {
      s0 = fmaf(x[2 * i],     __shfl(av, 16 * h + 2 * i),     s0);
      s1 = fmaf(x[2 * i + 1], __shfl(av, 16 * h + 2 * i + 1), s1);
    }
    float an = s0 + s1;
    an += __shfl_xor(an, 32);   // combine the two column-halves
    float mx = an;
#pragma unroll
    for (int off = 1; off < 32; off <<= 1) mx = fmaxf(mx, __shfl_xor(mx, off));
    av = an * __builtin_amdgcn_rcpf(mx);
    acc += __builtin_amdgcn_logf(mx) + offs[c * B_DIM + b];
  }

  float sv = av * __builtin_amdgcn_exp2f(endt[j] * INV_LN2);
#pragma unroll
  for (int off = 1; off < 32; off <<= 1) sv += __shfl_xor(sv, off);
  if (lane == 0) {
    float logZ = (acc + __builtin_amdgcn_logf(sv)) * LN2;
    // t=0 gold-path score terms
    int mk0 = mask[b];
    int tg0 = mk0 ? tags[b] : 1;
    float s0 = startt[tg0] + (mk0 ? em[(size_t)b * 32 + tg0] : 0.f);
    int mk1 = mask[B_DIM + b];
    if (mk0 && !mk1) s0 += endt[tg0];
    atomicAdd(out, logZ - s0);
  }
}

extern "C" void kernel_launch(void* const* d_in, const int* in_sizes, int n_in,
                              void* d_out, int out_size, void* d_ws, size_t ws_size,
                              hipStream_t stream) {
  const float* em   = (const float*)d_in[0];
  const int*   tags = (const int*)d_in[1];
  const float* wt   = (const float*)d_in[2];
  const int*   mask = (const int*)d_in[3];
  const float* tr   = (const float*)d_in[4];
  const float* stt  = (const float*)d_in[5];
  const float* ent  = (const float*)d_in[6];
  float* out = (float*)d_out;

  float* offs = (float*)d_ws;                          // CHUNKS*B floats (32 KB)
  uint32_t* mats = (uint32_t*)(offs + CHUNKS * B_DIM); // CHUNKS*B*512 u32 (~16.8 MB)

  hipMemsetAsync(out, 0, sizeof(float) * out_size, stream);
  chunk_kernel<<<(CHUNKS * B_DIM) / 4, 256, 0, stream>>>(em, tags, wt, mask, tr, ent, mats, offs, out);
  combine_kernel<<<B_DIM, 64, 0, stream>>>(em, tags, mask, stt, ent, mats, offs, out);
}

// Round 5
// 244.926 us; speedup vs baseline: 1.2791x; 1.0547x over previous
//
#include <hip/hip_runtime.h>
#include <hip/hip_bf16.h>
#include <stdint.h>

// CRF nllh = sum_b (logZ_b - score_b).
// logZ via chunked parallel scan in probability domain:
//   alpha_t = alpha_{t-1} * Q_t,  Q_t[i][j] = exp(trans[i][j]/w_{t-1} + em_t[j])
// 32 chunks of 64 steps: chunk computes X_c = (Q_{t0}..Q_{t1-1})^T with
// 32x32x16 bf16 MFMA pairs (X <- Q^T X, K=32 via C-chaining).
// KEY: a k-permutation sigma applied consistently to A and B makes the
// D-layout row-pairs land EXACTLY in B-operand slots -> zero cross-lane
// exchange per step. sigma is absorbed into the A-side transition constants.
// Q entries are built as bf16 BITS via magic-constant Schraudolph:
//   f = fma(tpre, 1/w, em*KSC + SBIAS + 2^23); bf16bits = low16(bits(f))
// Scalar rescale every 8 steps (log2 offset tracked). Depth-1 prefetch of
// (em,wt,mask). Gold-path score = lane-per-timestep epilogue in same kernel.

#define T_DIM 2048
#define B_DIM 256
#define M_DIM 32
#define CHUNKS 32
#define CLEN 64
#define KSC 184.6649652337873f      /* 128 / ln2 */
#define SBIAS2 12599160.66f         /* 2^23 + 127*128 - 7.34 (log-mean center) */

typedef __attribute__((ext_vector_type(8))) short short8;
typedef __attribute__((ext_vector_type(16))) float f32x16;

__device__ __forceinline__ int pack_bf16(float lo, float hi) {
  union { float f; uint32_t u; } a, b;
  a.f = lo; b.f = hi;
  // result = bf16(lo) | bf16(hi)<<16 (truncation rounding)
  return (int)__builtin_amdgcn_perm(b.u, a.u, 0x07060302u);
}

__device__ __forceinline__ int pack_lo16(int lo, int hi) {
  // (lo & 0xffff) | (hi << 16)
  return (int)__builtin_amdgcn_perm((uint32_t)hi, (uint32_t)lo, 0x05040100u);
}

// ---------------- chunk matrix products (MFMA) + score epilogue ----------------
// 256 threads = 4 independent waves, each handling one (chunk c, batch b) unit.
__global__ __launch_bounds__(256) void chunk_kernel(
    const float* __restrict__ em, const int* __restrict__ tags,
    const float* __restrict__ wt, const int* __restrict__ mask,
    const float* __restrict__ trans, const float* __restrict__ endt,
    uint32_t* __restrict__ mats, float* __restrict__ offs,
    float* __restrict__ out)
{
  int tid = threadIdx.x;
  int lane = tid & 63;
  int h = lane >> 5;        // wave half
  int r = lane & 31;        // A-row / B-col / D-col index
  int unit = blockIdx.x * 4 + (tid >> 6);   // = c*B + b
  int b = unit & (B_DIM - 1);
  int c = unit >> 8;
  int t0 = 1 + c * CLEN;
  int t1 = t0 + CLEN; if (t1 > T_DIM) t1 = T_DIM;

  // A-side transition constants with the k-permutation sigma folded in:
  // sigma1(8h+j) = (j<4 ? j : j+4) + 4h  (rows of X owned as D reg-pairs p0..p3)
  // sigma2 = sigma1 + 16                 (rows owned as D reg-pairs p4..p7)
  // A1[i=r][k=8h+j] = Q[sigma1][r] -> tpre[j]   = trans[sigma1][r]*KSC
  // A2[i=r][k=8h+j] = Q[sigma2][r] -> tpre[8+j] = trans[sigma2][r]*KSC
  float tpre[16];
#pragma unroll
  for (int j = 0; j < 8; ++j) {
    int row = ((j < 4) ? j : j + 4) + 4 * h;
    tpre[j]     = trans[row * 32 + r] * KSC;
    tpre[8 + j] = trans[(row + 16) * 32 + r] * KSC;
  }

  // X = identity in 32x32 D/C layout: reg p holds row (p&3)+8*(p>>2)+4h, col r
  f32x16 X;
#pragma unroll
  for (int p = 0; p < 16; ++p)
    X[p] = (((p & 3) + 8 * (p >> 2) + 4 * h) == r) ? 1.f : 0.f;

  float off2 = 0.f;   // accumulated log2 rescale offset

  // depth-1 prefetch registers
  float emv = em[((size_t)(t0 * B_DIM + b)) * 32 + r];
  float wv  = wt[(t0 - 1) * B_DIM + b];
  int   mkv = mask[t0 * B_DIM + b];

#pragma unroll 2
  for (int t = t0; t < t1; ++t) {
    // ---- prefetch t+1 (clamped; last prefetch is wasted but harmless) ----
    int tn = (t + 1 < T_DIM) ? (t + 1) : t;
    float emv_n = em[((size_t)(tn * B_DIM + b)) * 32 + r];
    float wv_n  = wt[(tn - 1) * B_DIM + b];
    int   mkv_n = mask[tn * B_DIM + b];

    if (mkv) {
      float rw = __builtin_amdgcn_rcpf(wv);
      float e  = fmaf(emv, KSC, SBIAS2);

      // Q^T A-fragments: magic-fma leaves bf16 bits in low16 of the float
      float qf[16];
#pragma unroll
      for (int j = 0; j < 16; ++j)
        qf[j] = fmaf(tpre[j], rw, e);
      union { int i[4]; short8 s; } af1, af2;
#pragma unroll
      for (int u = 0; u < 4; ++u) {
        af1.i[u] = pack_lo16(__float_as_int(qf[2 * u]),     __float_as_int(qf[2 * u + 1]));
        af2.i[u] = pack_lo16(__float_as_int(qf[8 + 2 * u]), __float_as_int(qf[8 + 2 * u + 1]));
      }

      // B operands = X's D reg-pairs verbatim (sigma absorbed the mismatch)
      union { int i[4]; short8 s; } b1, b2;
#pragma unroll
      for (int u = 0; u < 4; ++u) {
        b1.i[u] = pack_bf16(X[2 * u],     X[2 * u + 1]);
        b2.i[u] = pack_bf16(X[8 + 2 * u], X[8 + 2 * u + 1]);
      }

      f32x16 z;
#pragma unroll
      for (int u = 0; u < 16; ++u) z[u] = 0.f;
      f32x16 d = __builtin_amdgcn_mfma_f32_32x32x16_bf16(af1.s, b1.s, z, 0, 0, 0);
      X = __builtin_amdgcn_mfma_f32_32x32x16_bf16(af2.s, b2.s, d, 0, 0, 0);
    }

    if ((t & 7) == 7) {  // rescale: keep fp32/bf16 range safe
      float mx = X[0];
#pragma unroll
      for (int u = 1; u < 16; ++u) mx = fmaxf(mx, X[u]);
#pragma unroll
      for (int off = 1; off < 64; off <<= 1) mx = fmaxf(mx, __shfl_xor(mx, off));
      float sc = __builtin_amdgcn_rcpf(mx);
      off2 += __builtin_amdgcn_logf(mx);  // log2
#pragma unroll
      for (int u = 0; u < 16; ++u) X[u] *= sc;
    }

    emv = emv_n; wv = wv_n; mkv = mkv_n;
  }

  // store X as packed bf16 row-pairs: mp[pair*32 + col] = (X[2p][col], X[2p+1][col])
  uint32_t* mp = mats + (size_t)unit * 512;
#pragma unroll
  for (int u = 0; u < 8; ++u) {
    int pairIdx = (u & 1) + (u >> 1) * 4 + 2 * h;
    mp[pairIdx * 32 + r] = (uint32_t)pack_bf16(X[2 * u], X[2 * u + 1]);
  }
  if (lane == 0) offs[unit] = off2;

  // ---- score epilogue: one lane per timestep of this wave's range ----
  int t = t0 + lane;
  float ssc = 0.f;
  if (t < T_DIM) {
    int mk  = mask[t * B_DIM + b];
    int mkn = (t + 1 < T_DIM) ? mask[(t + 1) * B_DIM + b] : 0;
    int tg  = mk ? tags[t * B_DIM + b] : 1;
    int mkp = mask[(t - 1) * B_DIM + b];
    int tgp = mkp ? tags[(t - 1) * B_DIM + b] : 1;
    float w = wt[(t - 1) * B_DIM + b];
    if (mk)
      ssc = em[(size_t)(t * B_DIM + b) * 32 + tg]
          + trans[tgp * 32 + tg] * __builtin_amdgcn_rcpf(w);
    if (mk && !mkn) ssc += endt[tg];
  }
#pragma unroll
  for (int off = 32; off; off >>= 1) ssc += __shfl_xor(ssc, off);
  if (lane == 0) atomicAdd(out, -ssc);
}

// ---------------- combine chunks per batch + t=0 score ----------------
__global__ __launch_bounds__(64) void combine_kernel(
    const float* __restrict__ em, const int* __restrict__ tags,
    const int* __restrict__ mask, const float* __restrict__ startt,
    const float* __restrict__ endt, const uint32_t* __restrict__ mats,
    const float* __restrict__ offs, float* __restrict__ out)
{
  const float INV_LN2 = 1.44269504088896340736f;
  const float LN2 = 0.69314718055994530942f;
  int lane = threadIdx.x;
  int j = lane & 31;          // row handled by this lane (both halves hold av_j)
  int h = lane >> 5;          // which 16-column half this lane accumulates
  int b = blockIdx.x;
  int jp = j >> 1, jh = j & 1;

  float a0 = (startt[j] + em[(size_t)b * 32 + j]) * INV_LN2;  // log2 domain
  float c0 = a0;
#pragma unroll
  for (int off = 1; off < 32; off <<= 1) c0 = fmaxf(c0, __shfl_xor(c0, off));
  float av = __builtin_amdgcn_exp2f(a0 - c0);
  float acc = c0;  // accumulated log2 offset

  // depth-1 prefetch of chunk data
  const uint4* xr0 = (const uint4*)(mats + (size_t)b * 512 + jp * 32 + 16 * h);
  uint4 nv0 = xr0[0], nv1 = xr0[1];
  float noff = offs[b];

  for (int c = 0; c < CHUNKS; ++c) {
    uint4 v0 = nv0, v1 = nv1;
    float offc = noff;
    int cn = (c + 1 < CHUNKS) ? c + 1 : c;
    const uint4* xrn = (const uint4*)(mats + (size_t)(cn * B_DIM + b) * 512 + jp * 32 + 16 * h);
    nv0 = xrn[0]; nv1 = xrn[1];
    noff = offs[cn * B_DIM + b];

    float x[16];
    uint32_t u0[4] = {v0.x, v0.y, v0.z, v0.w};
    uint32_t u1[4] = {v1.x, v1.y, v1.z, v1.w};
#pragma unroll
    for (int e = 0; e < 4; ++e) {
      uint32_t bits0 = jh ? (u0[e] & 0xFFFF0000u) : (u0[e] << 16);
      uint32_t bits1 = jh ? (u1[e] & 0xFFFF0000u) : (u1[e] << 16);
      union { uint32_t uu; float f; } cv0, cv1;
      cv0.uu = bits0; cv1.uu = bits1;
      x[e] = cv0.f; x[4 + e] = cv1.f;
    }
    // x[0..3] = cols 16h+0..3 of row j, x[4..7] = cols 16h+4..7 (uint4 layout)
    float s0 = 0.f, s1 = 0.f;
#pragma unroll
    for (int i = 0; i < 4; ++i) {
      s0 = fmaf(x[i],     __shfl(av, 16 * h + i),     s0);
      s1 = fmaf(x[4 + i], __shfl(av, 16 * h + 4 + i), s1);
    }
    float an = s0 + s1;
    an += __shfl_xor(an, 32);   // combine the two column-halves
    float mx = an;
#pragma unroll
    for (int off = 1; off < 32; off <<= 1) mx = fmaxf(mx, __shfl_xor(mx, off));
    av = an * __builtin_amdgcn_rcpf(mx);
    acc += __builtin_amdgcn_logf(mx) + offc;
  }

  float sv = av * __builtin_amdgcn_exp2f(endt[j] * INV_LN2);
#pragma unroll
  for (int off = 1; off < 32; off <<= 1) sv += __shfl_xor(sv, off);
  if (lane == 0) {
    float logZ = (acc + __builtin_amdgcn_logf(sv)) * LN2;
    // t=0 gold-path score terms
    int mk0 = mask[b];
    int tg0 = mk0 ? tags[b] : 1;
    float s0 = startt[tg0] + (mk0 ? em[(size_t)b * 32 + tg0] : 0.f);
    int mk1 = mask[B_DIM + b];
    if (mk0 && !mk1) s0 += endt[tg0];
    atomicAdd(out, logZ - s0);
  }
}

extern "C" void kernel_launch(void* const* d_in, const int* in_sizes, int n_in,
                              void* d_out, int out_size, void* d_ws, size_t ws_size,
                              hipStream_t stream) {
  const float* em   = (const float*)d_in[0];
  const int*   tags = (const int*)d_in[1];
  const float* wt   = (const float*)d_in[2];
  const int*   mask = (const int*)d_in[3];
  const float* tr   = (const float*)d_in[4];
  const float* stt  = (const float*)d_in[5];
  const float* ent  = (const float*)d_in[6];
  float* out = (float*)d_out;

  float* offs = (float*)d_ws;                          // CHUNKS*B floats (32 KB)
  uint32_t* mats = (uint32_t*)(offs + CHUNKS * B_DIM); // CHUNKS*B*512 u32 (~16.8 MB)

  hipMemsetAsync(out, 0, sizeof(float) * out_size, stream);
  chunk_kernel<<<(CHUNKS * B_DIM) / 4, 256, 0, stream>>>(em, tags, wt, mask, tr, ent, mats, offs, out);
  combine_kernel<<<B_DIM, 64, 0, stream>>>(em, tags, mask, stt, ent, mats, offs, out);
}

// Round 6
// 240.460 us; speedup vs baseline: 1.3028x; 1.0186x over previous
//
#include <hip/hip_runtime.h>
#include <hip/hip_bf16.h>
#include <stdint.h>

// CRF nllh = sum_b (logZ_b - score_b).
// logZ via chunked parallel scan in probability domain:
//   alpha_t = alpha_{t-1} * Q_t,  Q_t[i][j] = exp(trans[i][j]/w_{t-1} + em_t[j])
// 32 chunks of 64 steps: chunk computes X_c = (Q_{t0}..Q_{t1-1})^T with
// 32x32x16 bf16 MFMA pairs (X <- Q^T X, K=32 via C-chaining).
// k-permutation sigma folded into A-side constants => D reg-pairs ARE the next
// B operands verbatim (zero cross-lane exchange per step).
// Q entries built as bf16 BITS via magic-constant Schraudolph:
//   f = fma(tpre, 1/w, em*KSC + SBIAS + 2^23); bf16bits = low16(bits(f))
// Memory schedule: wt/mask hoisted to ONE load per chunk (lane<->step, shfl
// broadcast + ballot bitmask); em rows loaded split-half (lanes 0-31 row t,
// lanes 32-63 row t+1) => one load instruction per TWO steps, prefetched one
// iteration (2 steps, ~1400 cy) ahead. Rescale every 8 steps (log2 offset).
// Gold-path score = lane-per-timestep epilogue in same kernel.

#define T_DIM 2048
#define B_DIM 256
#define M_DIM 32
#define CHUNKS 32
#define CLEN 64
#define KSC 184.6649652337873f      /* 128 / ln2 */
#define SBIAS2 12599160.66f         /* 2^23 + 127*128 - 7.34 (log-mean center) */

typedef __attribute__((ext_vector_type(8))) short short8;
typedef __attribute__((ext_vector_type(16))) float f32x16;

__device__ __forceinline__ int pack_bf16(float lo, float hi) {
  union { float f; uint32_t u; } a, b;
  a.f = lo; b.f = hi;
  // result = bf16(lo) | bf16(hi)<<16 (truncation rounding)
  return (int)__builtin_amdgcn_perm(b.u, a.u, 0x07060302u);
}

__device__ __forceinline__ int pack_lo16(int lo, int hi) {
  // (lo & 0xffff) | (hi << 16)
  return (int)__builtin_amdgcn_perm((uint32_t)hi, (uint32_t)lo, 0x05040100u);
}

// ---------------- chunk matrix products (MFMA) + score epilogue ----------------
// 256 threads = 4 independent waves, each handling one (chunk c, batch b) unit.
__global__ __launch_bounds__(256) void chunk_kernel(
    const float* __restrict__ em, const int* __restrict__ tags,
    const float* __restrict__ wt, const int* __restrict__ mask,
    const float* __restrict__ trans, const float* __restrict__ endt,
    uint32_t* __restrict__ mats, float* __restrict__ offs,
    float* __restrict__ out)
{
  int tid = threadIdx.x;
  int lane = tid & 63;
  int h = lane >> 5;        // wave half
  int r = lane & 31;        // A-row / B-col / D-col index
  int unit = blockIdx.x * 4 + (tid >> 6);   // = c*B + b
  int b = unit & (B_DIM - 1);
  int c = unit >> 8;
  int t0 = 1 + c * CLEN;
  int t1 = t0 + CLEN; if (t1 > T_DIM) t1 = T_DIM;

  // A-side transition constants with the k-permutation sigma folded in:
  // sigma1(8h+j) = (j<4 ? j : j+4) + 4h ; sigma2 = sigma1 + 16
  float tpre[16];
#pragma unroll
  for (int j = 0; j < 8; ++j) {
    int row = ((j < 4) ? j : j + 4) + 4 * h;
    tpre[j]     = trans[row * 32 + r] * KSC;
    tpre[8 + j] = trans[(row + 16) * 32 + r] * KSC;
  }

  // ---- hoisted per-chunk scalars: lane s <-> step t0+s ----
  float wv_l = wt[(t0 - 1 + lane) * B_DIM + b];       // t0-1+63 <= 2047 always
  float rwv  = __builtin_amdgcn_rcpf(wv_l);
  int tmk = t0 + lane; if (tmk > T_DIM - 1) tmk = T_DIM - 1;
  uint64_t mkbits = __ballot(mask[tmk * B_DIM + b] != 0);

  // X = identity in 32x32 D/C layout: reg p holds row (p&3)+8*(p>>2)+4h, col r
  f32x16 X;
#pragma unroll
  for (int p = 0; p < 16; ++p)
    X[p] = (((p & 3) + 8 * (p >> 2) + 4 * h) == r) ? 1.f : 0.f;

  float off2 = 0.f;   // accumulated log2 rescale offset

  // em rows t0 (half 0) / t0+1 (half 1)
  float emv = em[((size_t)((t0 + h) * B_DIM + b)) * 32 + r];

  auto step = [&](float e_em, int s) {
    float rw = __shfl(rwv, s);
    float e  = fmaf(e_em, KSC, SBIAS2);
    // Q^T A-fragments: magic-fma leaves bf16 bits in low16 of the float
    float qf[16];
#pragma unroll
    for (int j = 0; j < 16; ++j)
      qf[j] = fmaf(tpre[j], rw, e);
    union { int i[4]; short8 s; } af1, af2;
#pragma unroll
    for (int u = 0; u < 4; ++u) {
      af1.i[u] = pack_lo16(__float_as_int(qf[2 * u]),     __float_as_int(qf[2 * u + 1]));
      af2.i[u] = pack_lo16(__float_as_int(qf[8 + 2 * u]), __float_as_int(qf[8 + 2 * u + 1]));
    }
    // B operands = X's D reg-pairs verbatim (sigma absorbed the mismatch)
    union { int i[4]; short8 s; } b1, b2;
#pragma unroll
    for (int u = 0; u < 4; ++u) {
      b1.i[u] = pack_bf16(X[2 * u],     X[2 * u + 1]);
      b2.i[u] = pack_bf16(X[8 + 2 * u], X[8 + 2 * u + 1]);
    }
    f32x16 z;
#pragma unroll
    for (int u = 0; u < 16; ++u) z[u] = 0.f;
    f32x16 d = __builtin_amdgcn_mfma_f32_32x32x16_bf16(af1.s, b1.s, z, 0, 0, 0);
    X = __builtin_amdgcn_mfma_f32_32x32x16_bf16(af2.s, b2.s, d, 0, 0, 0);
  };

  for (int it = 0; it < CLEN / 2; ++it) {
    int tA = t0 + 2 * it;          // odd, always < t1
    // ---- prefetch rows tA+2 (h=0) / tA+3 (h=1), clamped ----
    int tn = tA + 2 + h; if (tn > T_DIM - 1) tn = T_DIM - 1;
    float emv_n = em[((size_t)(tn * B_DIM + b)) * 32 + r];

    float sw = __shfl_xor(emv, 32);

    // step A (t = tA): half 0 holds row tA natively
    int sA = 2 * it;
    if ((mkbits >> sA) & 1)
      step(h ? sw : emv, sA);

    // step B (t = tA+1): half 1 holds row tA+1 natively
    int sB = 2 * it + 1;
    if ((tA + 1 < t1) && ((mkbits >> sB) & 1))
      step(h ? emv : sw, sB);

    if ((it & 3) == 3) {  // rescale every 8 steps: keep fp32/bf16 range safe
      float mx = X[0];
#pragma unroll
      for (int u = 1; u < 16; ++u) mx = fmaxf(mx, X[u]);
#pragma unroll
      for (int off = 1; off < 64; off <<= 1) mx = fmaxf(mx, __shfl_xor(mx, off));
      float sc = __builtin_amdgcn_rcpf(mx);
      off2 += __builtin_amdgcn_logf(mx);  // log2
#pragma unroll
      for (int u = 0; u < 16; ++u) X[u] *= sc;
    }

    emv = emv_n;
  }

  // store X as packed bf16 row-pairs: mp[pair*32 + col] = (X[2p][col], X[2p+1][col])
  uint32_t* mp = mats + (size_t)unit * 512;
#pragma unroll
  for (int u = 0; u < 8; ++u) {
    int pairIdx = (u & 1) + (u >> 1) * 4 + 2 * h;
    mp[pairIdx * 32 + r] = (uint32_t)pack_bf16(X[2 * u], X[2 * u + 1]);
  }
  if (lane == 0) offs[unit] = off2;

  // ---- score epilogue: one lane per timestep of this wave's range ----
  int t = t0 + lane;
  float ssc = 0.f;
  if (t < T_DIM) {
    int mk  = mask[t * B_DIM + b];
    int mkn = (t + 1 < T_DIM) ? mask[(t + 1) * B_DIM + b] : 0;
    int tg  = mk ? tags[t * B_DIM + b] : 1;
    int mkp = mask[(t - 1) * B_DIM + b];
    int tgp = mkp ? tags[(t - 1) * B_DIM + b] : 1;
    if (mk)
      ssc = em[(size_t)(t * B_DIM + b) * 32 + tg]
          + trans[tgp * 32 + tg] * rwv;   // rwv = rcp(wt[t-1]) for this lane
    if (mk && !mkn) ssc += endt[tg];
  }
#pragma unroll
  for (int off = 32; off; off >>= 1) ssc += __shfl_xor(ssc, off);
  if (lane == 0) atomicAdd(out, -ssc);
}

// ---------------- combine chunks per batch + t=0 score ----------------
__global__ __launch_bounds__(64) void combine_kernel(
    const float* __restrict__ em, const int* __restrict__ tags,
    const int* __restrict__ mask, const float* __restrict__ startt,
    const float* __restrict__ endt, const uint32_t* __restrict__ mats,
    const float* __restrict__ offs, float* __restrict__ out)
{
  const float INV_LN2 = 1.44269504088896340736f;
  const float LN2 = 0.69314718055994530942f;
  int lane = threadIdx.x;
  int j = lane & 31;          // row handled by this lane (both halves hold av_j)
  int h = lane >> 5;          // which 16-column half this lane accumulates
  int b = blockIdx.x;
  int jp = j >> 1, jh = j & 1;

  float a0 = (startt[j] + em[(size_t)b * 32 + j]) * INV_LN2;  // log2 domain
  float c0 = a0;
#pragma unroll
  for (int off = 1; off < 32; off <<= 1) c0 = fmaxf(c0, __shfl_xor(c0, off));
  float av = __builtin_amdgcn_exp2f(a0 - c0);
  float acc = c0;  // accumulated log2 offset

  // depth-1 prefetch of chunk data
  const uint4* xr0 = (const uint4*)(mats + (size_t)b * 512 + jp * 32 + 16 * h);
  uint4 nv0 = xr0[0], nv1 = xr0[1];
  float noff = offs[b];

  for (int c = 0; c < CHUNKS; ++c) {
    uint4 v0 = nv0, v1 = nv1;
    float offc = noff;
    int cn = (c + 1 < CHUNKS) ? c + 1 : c;
    const uint4* xrn = (const uint4*)(mats + (size_t)(cn * B_DIM + b) * 512 + jp * 32 + 16 * h);
    nv0 = xrn[0]; nv1 = xrn[1];
    noff = offs[cn * B_DIM + b];

    float x[8];
    uint32_t u0[4] = {v0.x, v0.y, v0.z, v0.w};
    uint32_t u1[4] = {v1.x, v1.y, v1.z, v1.w};
#pragma unroll
    for (int e = 0; e < 4; ++e) {
      uint32_t bits0 = jh ? (u0[e] & 0xFFFF0000u) : (u0[e] << 16);
      uint32_t bits1 = jh ? (u1[e] & 0xFFFF0000u) : (u1[e] << 16);
      union { uint32_t uu; float f; } cv0, cv1;
      cv0.uu = bits0; cv1.uu = bits1;
      x[e] = cv0.f; x[4 + e] = cv1.f;
    }
    float s0 = 0.f, s1 = 0.f;
#pragma unroll
    for (int i = 0; i < 4; ++i) {
      s0 = fmaf(x[i],     __shfl(av, 16 * h + i),     s0);
      s1 = fmaf(x[4 + i], __shfl(av, 16 * h + 4 + i), s1);
    }
    float an = s0 + s1;
    an += __shfl_xor(an, 32);   // combine the two column-halves
    float mx = an;
#pragma unroll
    for (int off = 1; off < 32; off <<= 1) mx = fmaxf(mx, __shfl_xor(mx, off));
    av = an * __builtin_amdgcn_rcpf(mx);
    acc += __builtin_amdgcn_logf(mx) + offc;
  }

  float sv = av * __builtin_amdgcn_exp2f(endt[j] * INV_LN2);
#pragma unroll
  for (int off = 1; off < 32; off <<= 1) sv += __shfl_xor(sv, off);
  if (lane == 0) {
    float logZ = (acc + __builtin_amdgcn_logf(sv)) * LN2;
    // t=0 gold-path score terms
    int mk0 = mask[b];
    int tg0 = mk0 ? tags[b] : 1;
    float s0 = startt[tg0] + (mk0 ? em[(size_t)b * 32 + tg0] : 0.f);
    int mk1 = mask[B_DIM + b];
    if (mk0 && !mk1) s0 += endt[tg0];
    atomicAdd(out, logZ - s0);
  }
}

extern "C" void kernel_launch(void* const* d_in, const int* in_sizes, int n_in,
                              void* d_out, int out_size, void* d_ws, size_t ws_size,
                              hipStream_t stream) {
  const float* em   = (const float*)d_in[0];
  const int*   tags = (const int*)d_in[1];
  const float* wt   = (const float*)d_in[2];
  const int*   mask = (const int*)d_in[3];
  const float* tr   = (const float*)d_in[4];
  const float* stt  = (const float*)d_in[5];
  const float* ent  = (const float*)d_in[6];
  float* out = (float*)d_out;

  float* offs = (float*)d_ws;                          // CHUNKS*B floats (32 KB)
  uint32_t* mats = (uint32_t*)(offs + CHUNKS * B_DIM); // CHUNKS*B*512 u32 (~16.8 MB)

  hipMemsetAsync(out, 0, sizeof(float) * out_size, stream);
  chunk_kernel<<<(CHUNKS * B_DIM) / 4, 256, 0, stream>>>(em, tags, wt, mask, tr, ent, mats, offs, out);
  combine_kernel<<<B_DIM, 64, 0, stream>>>(em, tags, mask, stt, ent, mats, offs, out);
}

// Round 7
// 208.120 us; speedup vs baseline: 1.5053x; 1.1554x over previous
//
#include <hip/hip_runtime.h>
#include <hip/hip_bf16.h>
#include <stdint.h>

// CRF nllh = sum_b (logZ_b - score_b).
// logZ via chunked parallel scan in probability domain:
//   alpha_t = alpha_{t-1} * Q_t,  Q_t[i][j] = exp(trans[i][j]/w_{t-1} + em_t[j])
// 32 chunks of 64 steps: chunk computes X_c = (Q_{t0}..Q_{t1-1})^T with
// 32x32x16 bf16 MFMA pairs (X <- Q^T X, K=32 via C-chaining).
// k-permutation sigma folded into A-side constants => D reg-pairs ARE the next
// B operands verbatim (zero cross-lane exchange per step).
// Q entries built as bf16 BITS via magic-constant Schraudolph:
//   f = fma(tpre, 1/w, em*KSC + SBIAS + 2^23); bf16bits = low16(bits(f))
// ILP=2: each wave runs TWO independent chains (batches b, b+1; shared tpre)
// to overlap the serial pack->MFMA->MFMA chains. wt/mask hoisted to one load
// per chunk (lane<->step, readlane broadcast + ballot bitmask); em rows loaded
// split-half (lanes 0-31 row t, lanes 32-63 row t+1) with DEPTH-2 prefetch
// (~4 steps ahead > HBM latency). Rescale every 8 steps (log2 offset).
// Gold-path score = lane-per-timestep epilogue in same kernel.

#define T_DIM 2048
#define B_DIM 256
#define M_DIM 32
#define CHUNKS 32
#define CLEN 64
#define KSC 184.6649652337873f      /* 128 / ln2 */
#define SBIAS2 12599160.66f         /* 2^23 + 127*128 - 7.34 (log-mean center) */

typedef __attribute__((ext_vector_type(8))) short short8;
typedef __attribute__((ext_vector_type(16))) float f32x16;

__device__ __forceinline__ int pack_bf16(float lo, float hi) {
  union { float f; uint32_t u; } a, b;
  a.f = lo; b.f = hi;
  // result = bf16(lo) | bf16(hi)<<16 (truncation rounding)
  return (int)__builtin_amdgcn_perm(b.u, a.u, 0x07060302u);
}

__device__ __forceinline__ int pack_lo16(int lo, int hi) {
  // (lo & 0xffff) | (hi << 16)
  return (int)__builtin_amdgcn_perm((uint32_t)hi, (uint32_t)lo, 0x05040100u);
}

// ---------------- chunk matrix products (MFMA) + score epilogue ----------------
// 256 threads = 4 waves; each wave handles units 2w and 2w+1 (= chunk c,
// batches b0=2k, b1=2k+1).
__global__ __launch_bounds__(256) void chunk_kernel(
    const float* __restrict__ em, const int* __restrict__ tags,
    const float* __restrict__ wt, const int* __restrict__ mask,
    const float* __restrict__ trans, const float* __restrict__ endt,
    uint32_t* __restrict__ mats, float* __restrict__ offs,
    float* __restrict__ out)
{
  int tid = threadIdx.x;
  int lane = tid & 63;
  int h = lane >> 5;        // wave half
  int r = lane & 31;        // A-row / B-col / D-col index
  int wid = blockIdx.x * 4 + (tid >> 6);
  int unit0 = 2 * wid, unit1 = unit0 + 1;   // same chunk, adjacent batches
  int b0 = unit0 & (B_DIM - 1), b1 = b0 + 1;
  int c = unit0 >> 8;
  int t0 = 1 + c * CLEN;
  int t1 = t0 + CLEN; if (t1 > T_DIM) t1 = T_DIM;

  // A-side transition constants with the k-permutation sigma folded in:
  // sigma1(8h+j) = (j<4 ? j : j+4) + 4h ; sigma2 = sigma1 + 16  (shared by both chains)
  float tpre[16];
#pragma unroll
  for (int j = 0; j < 8; ++j) {
    int row = ((j < 4) ? j : j + 4) + 4 * h;
    tpre[j]     = trans[row * 32 + r] * KSC;
    tpre[8 + j] = trans[(row + 16) * 32 + r] * KSC;
  }

  // ---- hoisted per-chunk scalars: lane s <-> step t0+s ----
  float rwv0 = __builtin_amdgcn_rcpf(wt[(t0 - 1 + lane) * B_DIM + b0]);
  float rwv1 = __builtin_amdgcn_rcpf(wt[(t0 - 1 + lane) * B_DIM + b1]);
  int tmk = t0 + lane; if (tmk > T_DIM - 1) tmk = T_DIM - 1;
  uint64_t mk0 = __ballot(mask[tmk * B_DIM + b0] != 0);
  uint64_t mk1 = __ballot(mask[tmk * B_DIM + b1] != 0);

  // X = identity in 32x32 D/C layout: reg p holds row (p&3)+8*(p>>2)+4h, col r
  f32x16 X0, X1;
#pragma unroll
  for (int p = 0; p < 16; ++p) {
    float v = (((p & 3) + 8 * (p >> 2) + 4 * h) == r) ? 1.f : 0.f;
    X0[p] = v; X1[p] = v;
  }
  f32x16 z;
#pragma unroll
  for (int u = 0; u < 16; ++u) z[u] = 0.f;

  float off0 = 0.f, off1 = 0.f;   // accumulated log2 rescale offsets

  // em rows: half 0 holds row t, half 1 row t+1; depth-2 prefetch
  float emv0 = em[((size_t)((t0 + h) * B_DIM + b0)) * 32 + r];
  float emv1 = em[((size_t)((t0 + h) * B_DIM + b1)) * 32 + r];
  int tpf = t0 + 2 + h; if (tpf > T_DIM - 1) tpf = T_DIM - 1;
  float emp0 = em[((size_t)(tpf * B_DIM + b0)) * 32 + r];
  float emp1 = em[((size_t)(tpf * B_DIM + b1)) * 32 + r];

  auto step = [&](f32x16& X, float e_em, float rw) {
    float e = fmaf(e_em, KSC, SBIAS2);
    // Q^T A-fragments: magic-fma leaves bf16 bits in low16 of the float
    float qf[16];
#pragma unroll
    for (int j = 0; j < 16; ++j)
      qf[j] = fmaf(tpre[j], rw, e);
    union { int i[4]; short8 s; } af1, af2;
#pragma unroll
    for (int u = 0; u < 4; ++u) {
      af1.i[u] = pack_lo16(__float_as_int(qf[2 * u]),     __float_as_int(qf[2 * u + 1]));
      af2.i[u] = pack_lo16(__float_as_int(qf[8 + 2 * u]), __float_as_int(qf[8 + 2 * u + 1]));
    }
    // B operands = X's D reg-pairs verbatim (sigma absorbed the mismatch)
    union { int i[4]; short8 s; } b1_, b2_;
#pragma unroll
    for (int u = 0; u < 4; ++u) {
      b1_.i[u] = pack_bf16(X[2 * u],     X[2 * u + 1]);
      b2_.i[u] = pack_bf16(X[8 + 2 * u], X[8 + 2 * u + 1]);
    }
    f32x16 d = __builtin_amdgcn_mfma_f32_32x32x16_bf16(af1.s, b1_.s, z, 0, 0, 0);
    X = __builtin_amdgcn_mfma_f32_32x32x16_bf16(af2.s, b2_.s, d, 0, 0, 0);
  };

  auto rescale = [&](f32x16& X, float& off2) {
    float mx = X[0];
#pragma unroll
    for (int u = 1; u < 16; ++u) mx = fmaxf(mx, X[u]);
#pragma unroll
    for (int off = 1; off < 64; off <<= 1) mx = fmaxf(mx, __shfl_xor(mx, off));
    float sc = __builtin_amdgcn_rcpf(mx);
    off2 += __builtin_amdgcn_logf(mx);  // log2
#pragma unroll
    for (int u = 0; u < 16; ++u) X[u] *= sc;
  };

  for (int it = 0; it < CLEN / 2; ++it) {
    // ---- prefetch rows for iteration it+2 (4 steps ahead), clamped ----
    int tn = t0 + 2 * it + 4 + h; if (tn > T_DIM - 1) tn = T_DIM - 1;
    float emn0 = em[((size_t)(tn * B_DIM + b0)) * 32 + r];
    float emn1 = em[((size_t)(tn * B_DIM + b1)) * 32 + r];

    float sw0 = __shfl_xor(emv0, 32);
    float sw1 = __shfl_xor(emv1, 32);

    int sA = 2 * it, sB = sA + 1;
    // step A (t = t0+sA): half 0 holds that row natively
    if ((mk0 >> sA) & 1) step(X0, h ? sw0 : emv0, __shfl(rwv0, sA));
    if ((mk1 >> sA) & 1) step(X1, h ? sw1 : emv1, __shfl(rwv1, sA));
    // step B (t = t0+sB): half 1 holds that row natively
    if (t0 + sB < t1) {
      if ((mk0 >> sB) & 1) step(X0, h ? emv0 : sw0, __shfl(rwv0, sB));
      if ((mk1 >> sB) & 1) step(X1, h ? emv1 : sw1, __shfl(rwv1, sB));
    }

    if ((it & 3) == 3) {  // rescale every 8 steps: keep fp32/bf16 range safe
      rescale(X0, off0);
      rescale(X1, off1);
    }

    emv0 = emp0; emp0 = emn0;
    emv1 = emp1; emp1 = emn1;
  }

  // store X as packed bf16 row-pairs: mp[pair*32 + col] = (X[2p][col], X[2p+1][col])
  uint32_t* mp0 = mats + (size_t)unit0 * 512;
  uint32_t* mp1 = mats + (size_t)unit1 * 512;
#pragma unroll
  for (int u = 0; u < 8; ++u) {
    int pairIdx = (u & 1) + (u >> 1) * 4 + 2 * h;
    mp0[pairIdx * 32 + r] = (uint32_t)pack_bf16(X0[2 * u], X0[2 * u + 1]);
    mp1[pairIdx * 32 + r] = (uint32_t)pack_bf16(X1[2 * u], X1[2 * u + 1]);
  }
  if (lane == 0) { offs[unit0] = off0; offs[unit1] = off1; }

  // ---- score epilogue: one lane per timestep, both chains ----
  int t = t0 + lane;
  float ssc = 0.f;
  if (t < T_DIM) {
    // chain 0
    int mk  = mask[t * B_DIM + b0];
    int mkn = (t + 1 < T_DIM) ? mask[(t + 1) * B_DIM + b0] : 0;
    int tg  = mk ? tags[t * B_DIM + b0] : 1;
    int mkp = mask[(t - 1) * B_DIM + b0];
    int tgp = mkp ? tags[(t - 1) * B_DIM + b0] : 1;
    if (mk)
      ssc = em[(size_t)(t * B_DIM + b0) * 32 + tg]
          + trans[tgp * 32 + tg] * rwv0;
    if (mk && !mkn) ssc += endt[tg];
    // chain 1
    mk  = mask[t * B_DIM + b1];
    mkn = (t + 1 < T_DIM) ? mask[(t + 1) * B_DIM + b1] : 0;
    tg  = mk ? tags[t * B_DIM + b1] : 1;
    mkp = mask[(t - 1) * B_DIM + b1];
    tgp = mkp ? tags[(t - 1) * B_DIM + b1] : 1;
    if (mk)
      ssc += em[(size_t)(t * B_DIM + b1) * 32 + tg]
           + trans[tgp * 32 + tg] * rwv1;
    if (mk && !mkn) ssc += endt[tg];
  }
#pragma unroll
  for (int off = 32; off; off >>= 1) ssc += __shfl_xor(ssc, off);
  if (lane == 0) atomicAdd(out, -ssc);
}

// ---------------- combine chunks per batch + t=0 score ----------------
__global__ __launch_bounds__(64) void combine_kernel(
    const float* __restrict__ em, const int* __restrict__ tags,
    const int* __restrict__ mask, const float* __restrict__ startt,
    const float* __restrict__ endt, const uint32_t* __restrict__ mats,
    const float* __restrict__ offs, float* __restrict__ out)
{
  const float INV_LN2 = 1.44269504088896340736f;
  const float LN2 = 0.69314718055994530942f;
  int lane = threadIdx.x;
  int j = lane & 31;          // row handled by this lane (both halves hold av_j)
  int h = lane >> 5;          // which 16-column half this lane accumulates
  int b = blockIdx.x;
  int jp = j >> 1, jh = j & 1;

  float a0 = (startt[j] + em[(size_t)b * 32 + j]) * INV_LN2;  // log2 domain
  float c0 = a0;
#pragma unroll
  for (int off = 1; off < 32; off <<= 1) c0 = fmaxf(c0, __shfl_xor(c0, off));
  float av = __builtin_amdgcn_exp2f(a0 - c0);
  float acc = c0;  // accumulated log2 offset

  // depth-1 prefetch of chunk data
  const uint4* xr0 = (const uint4*)(mats + (size_t)b * 512 + jp * 32 + 16 * h);
  uint4 nv0 = xr0[0], nv1 = xr0[1];
  float noff = offs[b];

  for (int c = 0; c < CHUNKS; ++c) {
    uint4 v0 = nv0, v1 = nv1;
    float offc = noff;
    int cn = (c + 1 < CHUNKS) ? c + 1 : c;
    const uint4* xrn = (const uint4*)(mats + (size_t)(cn * B_DIM + b) * 512 + jp * 32 + 16 * h);
    nv0 = xrn[0]; nv1 = xrn[1];
    noff = offs[cn * B_DIM + b];

    float x[8];
    uint32_t u0[4] = {v0.x, v0.y, v0.z, v0.w};
    uint32_t u1[4] = {v1.x, v1.y, v1.z, v1.w};
#pragma unroll
    for (int e = 0; e < 4; ++e) {
      uint32_t bits0 = jh ? (u0[e] & 0xFFFF0000u) : (u0[e] << 16);
      uint32_t bits1 = jh ? (u1[e] & 0xFFFF0000u) : (u1[e] << 16);
      union { uint32_t uu; float f; } cv0, cv1;
      cv0.uu = bits0; cv1.uu = bits1;
      x[e] = cv0.f; x[4 + e] = cv1.f;
    }
    float s0 = 0.f, s1 = 0.f;
#pragma unroll
    for (int i = 0; i < 4; ++i) {
      s0 = fmaf(x[i],     __shfl(av, 16 * h + i),     s0);
      s1 = fmaf(x[4 + i], __shfl(av, 16 * h + 4 + i), s1);
    }
    float an = s0 + s1;
    an += __shfl_xor(an, 32);   // combine the two column-halves
    float mx = an;
#pragma unroll
    for (int off = 1; off < 32; off <<= 1) mx = fmaxf(mx, __shfl_xor(mx, off));
    av = an * __builtin_amdgcn_rcpf(mx);
    acc += __builtin_amdgcn_logf(mx) + offc;
  }

  float sv = av * __builtin_amdgcn_exp2f(endt[j] * INV_LN2);
#pragma unroll
  for (int off = 1; off < 32; off <<= 1) sv += __shfl_xor(sv, off);
  if (lane == 0) {
    float logZ = (acc + __builtin_amdgcn_logf(sv)) * LN2;
    // t=0 gold-path score terms
    int mk0 = mask[b];
    int tg0 = mk0 ? tags[b] : 1;
    float s0 = startt[tg0] + (mk0 ? em[(size_t)b * 32 + tg0] : 0.f);
    int mk1 = mask[B_DIM + b];
    if (mk0 && !mk1) s0 += endt[tg0];
    atomicAdd(out, logZ - s0);
  }
}

extern "C" void kernel_launch(void* const* d_in, const int* in_sizes, int n_in,
                              void* d_out, int out_size, void* d_ws, size_t ws_size,
                              hipStream_t stream) {
  const float* em   = (const float*)d_in[0];
  const int*   tags = (const int*)d_in[1];
  const float* wt   = (const float*)d_in[2];
  const int*   mask = (const int*)d_in[3];
  const float* tr   = (const float*)d_in[4];
  const float* stt  = (const float*)d_in[5];
  const float* ent  = (const float*)d_in[6];
  float* out = (float*)d_out;

  float* offs = (float*)d_ws;                          // CHUNKS*B floats (32 KB)
  uint32_t* mats = (uint32_t*)(offs + CHUNKS * B_DIM); // CHUNKS*B*512 u32 (~16.8 MB)

  hipMemsetAsync(out, 0, sizeof(float) * out_size, stream);
  chunk_kernel<<<(CHUNKS * B_DIM) / 8, 256, 0, stream>>>(em, tags, wt, mask, tr, ent, mats, offs, out);
  combine_kernel<<<B_DIM, 64, 0, stream>>>(em, tags, mask, stt, ent, mats, offs, out);
}